// Round 8
// baseline (2869.944 us; speedup 1.0000x reference)
//
#include <hip/hip_runtime.h>

#define NM 1200
#define NMP 1280          // K padded to 8*160
#define PP 719400         // NM*(NM-1)/2
#define HID 128
#define RANK 64
#define SDP_ITERS 100
#define SDP_BLOCKS 120
#define SDP_ROWS 10       // 120*10 = 1200

// ---------------- ws layout (floats) ----------------
#define OFF_S      0
#define OFF_SUMW2  1600
#define OFF_CNT    1601
#define OFF_GEN    1602
#define OFF_CVEC   1664
#define OFF_W1S    1792
#define OFF_WVEC   6912
#define OFF_WMAT   726400
#define OFF_VA     2262400
#define OFF_VB     2344320
#define OFF_SPART  726400     // 64*1600 floats, aliases Wmat (consumed by reduce_S first)

__device__ __forceinline__ float wave_reduce_sum(float v) {
#pragma unroll
    for (int o = 32; o > 0; o >>= 1) v += __shfl_xor(v, o, 64);
    return v;
}

// grid-wide barrier: agent-scope atomics (per-XCD L2 non-coherent -> must not
// rely on plain loads). Generation counter; only thread 0 spins.
__device__ __forceinline__ void gsync(unsigned* cnt, unsigned* gen, unsigned nblk) {
    __syncthreads();
    if (threadIdx.x == 0) {
        __threadfence();
        unsigned g = __hip_atomic_load(gen, __ATOMIC_RELAXED, __HIP_MEMORY_SCOPE_AGENT);
        unsigned a = __hip_atomic_fetch_add(cnt, 1u, __ATOMIC_ACQ_REL, __HIP_MEMORY_SCOPE_AGENT);
        if (a == nblk - 1u) {
            __hip_atomic_store(cnt, 0u, __ATOMIC_RELAXED, __HIP_MEMORY_SCOPE_AGENT);
            __hip_atomic_fetch_add(gen, 1u, __ATOMIC_RELEASE, __HIP_MEMORY_SCOPE_AGENT);
        } else {
            while (__hip_atomic_load(gen, __ATOMIC_ACQUIRE, __HIP_MEMORY_SCOPE_AGENT) == g) {
                __builtin_amdgcn_s_sleep(2);
            }
        }
    }
    __syncthreads();
}

// ---- pass 1: S = [x|1]^T [x|1]; 2000 blocks for latency hiding; 64 partial slots ----
#define SBLK 2000
__global__ __launch_bounds__(256) void stats_kernel(const float* __restrict__ x,
                                                    float* __restrict__ Spart) {
    __shared__ __align__(8) float tile[40 * 48];
    __shared__ float Sacc[48 * 48];
    const int tid = threadIdx.x;
    for (int i = tid; i < 48 * 48; i += 256) Sacc[i] = 0.f;
    // constant cols: 39 = ones feature, 40..47 = pad
    for (int r = tid; r < 40; r += 256) {
        tile[r * 48 + 39] = 1.f;
#pragma unroll
        for (int c = 40; c < 48; ++c) tile[r * 48 + c] = 0.f;
    }
    const int bid = blockIdx.x;
    const int nt = (bid < SBLK - 2) ? 9 : ((bid == SBLK - 2) ? 3 : 0);
    const float* __restrict__ xp = x + (size_t)bid * 360 * 39;

    const int z  = tid >> 6;
    const int ln = tid & 63;
    const int ty = ln >> 3, tx = ln & 7;

    float acc[6][6];
#pragma unroll
    for (int a = 0; a < 6; ++a)
#pragma unroll
        for (int b = 0; b < 6; ++b) acc[a][b] = 0.f;

    for (int t = 0; t < nt; ++t) {
        __syncthreads();
        const float* __restrict__ xg = xp + (size_t)t * 1560;
        for (int idx = tid; idx < 1560; idx += 256) {
            int rr = idx / 39, cc = idx - rr * 39;
            tile[rr * 48 + cc] = xg[idx];
        }
        __syncthreads();
#pragma unroll 2
        for (int kk = 0; kk < 10; ++kk) {
            const float* row = &tile[(kk * 4 + z) * 48];
            float2 a0 = *(const float2*)(row + ty * 6);
            float2 a1 = *(const float2*)(row + ty * 6 + 2);
            float2 a2 = *(const float2*)(row + ty * 6 + 4);
            float2 b0 = *(const float2*)(row + tx * 6);
            float2 b1 = *(const float2*)(row + tx * 6 + 2);
            float2 b2 = *(const float2*)(row + tx * 6 + 4);
            float av[6] = {a0.x, a0.y, a1.x, a1.y, a2.x, a2.y};
            float bv[6] = {b0.x, b0.y, b1.x, b1.y, b2.x, b2.y};
#pragma unroll
            for (int a = 0; a < 6; ++a)
#pragma unroll
                for (int b = 0; b < 6; ++b)
                    acc[a][b] = fmaf(av[a], bv[b], acc[a][b]);
        }
    }
    __syncthreads();
#pragma unroll
    for (int a = 0; a < 6; ++a)
#pragma unroll
        for (int b = 0; b < 6; ++b)
            atomicAdd(&Sacc[(ty * 6 + a) * 48 + tx * 6 + b], acc[a][b]);
    __syncthreads();
    float* out = Spart + (size_t)(bid & 63) * 1600;
    for (int i = tid; i < 1600; i += 256) {
        int r = i / 40, c = i - r * 40;
        atomicAdd(&out[i], Sacc[r * 48 + c]);
    }
}

// ---- reduce 64 partials -> S[40x40] ----
__global__ __launch_bounds__(256) void reduce_S(const float* __restrict__ Spart,
                                                float* __restrict__ S) {
    const int j = blockIdx.x * 256 + threadIdx.x;
    if (j >= 1600) return;
    float s = 0.f;
#pragma unroll 8
    for (int b = 0; b < 64; ++b) s += Spart[(size_t)b * 1600 + j];
    S[j] = s;
}

// ---- BN folding ----
__global__ __launch_bounds__(64) void bn_prep(const float* __restrict__ S,
                                              const float* __restrict__ W1,
                                              const float* __restrict__ gamma,
                                              const float* __restrict__ beta,
                                              float* __restrict__ W1s,
                                              float* __restrict__ cvec) {
    const int j = blockIdx.x;
    const int l = threadIdx.x;
    const float invP = 1.0f / (float)PP;
    float q = 0.f;
    for (int idx = l; idx < 39 * 39; idx += 64) {
        int a = idx / 39, b = idx - a * 39;
        q = fmaf(S[a * 40 + b], W1[a * HID + j] * W1[b * HID + j], q);
    }
    float s1 = (l < 39) ? (S[39 * 40 + l] * invP) * W1[l * HID + j] : 0.f;
    q = wave_reduce_sum(q);
    s1 = wave_reduce_sum(s1);
    float var = q * invP - s1 * s1;
    float scale = gamma[j] * (1.0f / sqrtf(var + 1e-5f));
    for (int a = l; a < 39; a += 64) W1s[a * HID + j] = W1[a * HID + j] * scale;
    if (l == 0) cvec[j] = -s1 * scale + beta[j];
}

// ---- fused MLP ----
__global__ __launch_bounds__(256, 1) void mlp_kernel(const float* __restrict__ x,
                                                     const float* __restrict__ W1s,
                                                     const float* __restrict__ cvec,
                                                     const float* __restrict__ W2,
                                                     const float* __restrict__ b2,
                                                     float* __restrict__ w,
                                                     float* __restrict__ sumw2) {
    __shared__ float xt[256 * 39];
    __shared__ float red[4];
    const size_t base = (size_t)blockIdx.x * 256;
    {
        const size_t g0 = base * 39;
        const size_t gmax = (size_t)PP * 39;
        for (int idx = threadIdx.x; idx < 256 * 39; idx += 256) {
            size_t g = g0 + idx;
            xt[idx] = (g < gmax) ? x[g] : 0.f;
        }
    }
    __syncthreads();

    float xr[39];
    {
        const float* xrow = &xt[threadIdx.x * 39];
#pragma unroll
        for (int k = 0; k < 39; ++k) xr[k] = xrow[k];
    }

    float wacc = 0.f;
#pragma unroll 1
    for (int c = 0; c < 2; ++c) {
        float acc[64];
#pragma unroll
        for (int jj = 0; jj < 64; ++jj) acc[jj] = cvec[c * 64 + jj];
#pragma unroll 3
        for (int k = 0; k < 39; ++k) {
            const float xk = xr[k];
            const float* wrow = &W1s[k * HID + c * 64];
#pragma unroll
            for (int jj = 0; jj < 64; ++jj) acc[jj] = fmaf(xk, wrow[jj], acc[jj]);
        }
#pragma unroll
        for (int jj = 0; jj < 64; ++jj)
            wacc = fmaf(fmaxf(acc[jj], 0.f), W2[c * 64 + jj], wacc);
    }

    const size_t p = base + threadIdx.x;
    const float wv = wacc + b2[0];
    float sq = 0.f;
    if (p < (size_t)PP) { w[p] = wv; sq = wv * wv; }
    sq = wave_reduce_sum(sq);
    if ((threadIdx.x & 63) == 0) red[threadIdx.x >> 6] = sq;
    __syncthreads();
    if (threadIdx.x == 0) atomicAdd(sumw2, red[0] + red[1] + red[2] + red[3]);
}

// ---- W build: stride NMP, zero pad cols (verified: bj in [75,80) writes zeros) ----
__global__ __launch_bounds__(256) void buildW(const float* __restrict__ w,
                                              float* __restrict__ W) {
    __shared__ float tile[16][17];
    const int bi = blockIdx.y, bj = blockIdx.x;   // bi<75, bj<80
    if (bi > bj) return;
    const int ty = threadIdx.x >> 4, tx = threadIdx.x & 15;
    const int i = bi * 16 + ty, j = bj * 16 + tx;
    float v = 0.f;
    if (i < j && j < NM) {
        int p = i * (NM - 1) - (i * (i - 1)) / 2 + (j - i - 1);
        v = w[p];
    }
    tile[ty][tx] = v;
    __syncthreads();
    if (bi == bj) {
        float o = (i < j) ? v : ((i > j) ? tile[tx][ty] : 0.f);
        W[(size_t)i * NMP + j] = o;
    } else {
        W[(size_t)i * NMP + j] = v;
        if (bj < 75)
            W[(size_t)(bj * 16 + ty) * NMP + (bi * 16 + tx)] = tile[tx][ty];
    }
}

// ---- fused SDP: v0norm + 100 power iterations in ONE kernel ----
// 120 blocks (co-resident: <= 256 CUs) x 512 thr; block owns 10 rows; 8 waves =
// 160-k slices. W via wave-uniform s_loads; V coalesced 256B/wave from L2/L3.
__global__ __launch_bounds__(512) void sdp_fused(const float* __restrict__ V0,
                                                 float* __restrict__ Va,
                                                 float* __restrict__ Vb,
                                                 const float* __restrict__ W,
                                                 const float* __restrict__ sumw2,
                                                 unsigned* __restrict__ cnt,
                                                 unsigned* __restrict__ gen) {
    __shared__ float part[8][SDP_ROWS][64];   // 20 KB
    const int tid = threadIdx.x;
    const int c = tid & 63;
    const int wv = __builtin_amdgcn_readfirstlane(tid >> 6);   // 0..7, uniform
    const int i0 = blockIdx.x * SDP_ROWS;

    // v0norm for our rows
    for (int rr = wv; rr < SDP_ROWS; rr += 8) {
        float v = V0[(size_t)(i0 + rr) * RANK + c];
        float s = wave_reduce_sum(v * v);
        Va[(size_t)(i0 + rr) * RANK + c] = v * (1.0f / sqrtf(s));
    }
    const float lr = 1.0f / (sqrtf(2.0f * sumw2[0]) + 1e-8f);
    gsync(cnt, gen, SDP_BLOCKS);

    const float* __restrict__ Wb = W + (size_t)i0 * NMP;
    const int k0 = wv * 160;

    for (int it = 0; it < SDP_ITERS; ++it) {
        const float* __restrict__ Vin = (it & 1) ? Vb : Va;
        float* __restrict__ Vout      = (it & 1) ? Va : Vb;
        float acc[SDP_ROWS];
#pragma unroll
        for (int r = 0; r < SDP_ROWS; ++r) acc[r] = 0.f;
        const float* __restrict__ vp = Vin + (size_t)k0 * RANK + c;
#pragma unroll 4
        for (int t = 0; t < 160; ++t) {
            const float vc = vp[(size_t)t * RANK];
#pragma unroll
            for (int r = 0; r < SDP_ROWS; ++r)
                acc[r] = fmaf(Wb[(size_t)r * NMP + k0 + t], vc, acc[r]);
        }
#pragma unroll
        for (int r = 0; r < SDP_ROWS; ++r) part[wv][r][c] = acc[r];
        __syncthreads();
        for (int rr = wv; rr < SDP_ROWS; rr += 8) {
            float s = 0.f;
#pragma unroll
            for (int q = 0; q < 8; ++q) s += part[q][rr][c];
            float y = Vin[(size_t)(i0 + rr) * RANK + c] + lr * s;
            float n = wave_reduce_sum(y * y);
            Vout[(size_t)(i0 + rr) * RANK + c] = y * (1.0f / sqrtf(n));
        }
        gsync(cnt, gen, SDP_BLOCKS);
    }
}

// ---- out = clip(V V^T, 0, 1) ----
__global__ __launch_bounds__(256) void vvt_kernel(const float* __restrict__ V,
                                                  float* __restrict__ out) {
    const int bi = blockIdx.y, bj = blockIdx.x;
    if (bi > bj) return;
    __shared__ __align__(16) float Ti[64][132];
    __shared__ __align__(16) float Tj[64][132];
    const int tid = threadIdx.x;
    for (int idx = tid; idx < 128 * 64; idx += 256) {
        int row = idx >> 6, k = idx & 63;
        int gi = bi * 128 + row, gj = bj * 128 + row;
        Ti[k][row] = (gi < NM) ? V[(size_t)gi * RANK + k] : 0.f;
        Tj[k][row] = (gj < NM) ? V[(size_t)gj * RANK + k] : 0.f;
    }
    __syncthreads();
    const int ty = tid >> 4, tx = tid & 15;
    float acc[8][8];
#pragma unroll
    for (int a = 0; a < 8; ++a)
#pragma unroll
        for (int b = 0; b < 8; ++b) acc[a][b] = 0.f;
    for (int k = 0; k < 64; ++k) {
        float4 a0 = *(const float4*)&Ti[k][ty * 8];
        float4 a1 = *(const float4*)&Ti[k][ty * 8 + 4];
        float4 b0 = *(const float4*)&Tj[k][tx * 8];
        float4 b1 = *(const float4*)&Tj[k][tx * 8 + 4];
        float av[8] = {a0.x, a0.y, a0.z, a0.w, a1.x, a1.y, a1.z, a1.w};
        float bv[8] = {b0.x, b0.y, b0.z, b0.w, b1.x, b1.y, b1.z, b1.w};
#pragma unroll
        for (int a = 0; a < 8; ++a)
#pragma unroll
            for (int b = 0; b < 8; ++b)
                acc[a][b] = fmaf(av[a], bv[b], acc[a][b]);
    }
#pragma unroll
    for (int a = 0; a < 8; ++a) {
        int i = bi * 128 + 8 * ty + a;
        if (i >= NM) break;
        int jb = bj * 128 + 8 * tx;
        if (jb + 7 < NM) {
            float4 s0 = {fminf(fmaxf(acc[a][0], 0.f), 1.f), fminf(fmaxf(acc[a][1], 0.f), 1.f),
                         fminf(fmaxf(acc[a][2], 0.f), 1.f), fminf(fmaxf(acc[a][3], 0.f), 1.f)};
            float4 s1 = {fminf(fmaxf(acc[a][4], 0.f), 1.f), fminf(fmaxf(acc[a][5], 0.f), 1.f),
                         fminf(fmaxf(acc[a][6], 0.f), 1.f), fminf(fmaxf(acc[a][7], 0.f), 1.f)};
            *(float4*)&out[(size_t)i * NM + jb] = s0;
            *(float4*)&out[(size_t)i * NM + jb + 4] = s1;
        } else {
#pragma unroll
            for (int b = 0; b < 8; ++b) {
                int j = jb + b;
                if (j < NM) out[(size_t)i * NM + j] = fminf(fmaxf(acc[a][b], 0.f), 1.f);
            }
        }
    }
    if (bi != bj) {
#pragma unroll
        for (int b = 0; b < 8; ++b) {
            int j = bj * 128 + 8 * tx + b;
            if (j >= NM) break;
            int ib = bi * 128 + 8 * ty;
            if (ib + 7 < NM) {
                float4 s0 = {fminf(fmaxf(acc[0][b], 0.f), 1.f), fminf(fmaxf(acc[1][b], 0.f), 1.f),
                             fminf(fmaxf(acc[2][b], 0.f), 1.f), fminf(fmaxf(acc[3][b], 0.f), 1.f)};
                float4 s1 = {fminf(fmaxf(acc[4][b], 0.f), 1.f), fminf(fmaxf(acc[5][b], 0.f), 1.f),
                             fminf(fmaxf(acc[6][b], 0.f), 1.f), fminf(fmaxf(acc[7][b], 0.f), 1.f)};
                *(float4*)&out[(size_t)j * NM + ib] = s0;
                *(float4*)&out[(size_t)j * NM + ib + 4] = s1;
            } else {
#pragma unroll
                for (int a = 0; a < 8; ++a) {
                    int i = ib + a;
                    if (i < NM) out[(size_t)j * NM + i] = fminf(fmaxf(acc[a][b], 0.f), 1.f);
                }
            }
        }
    }
}

extern "C" void kernel_launch(void* const* d_in, const int* in_sizes, int n_in,
                              void* d_out, int out_size, void* d_ws, size_t ws_size,
                              hipStream_t stream) {
    const float* x     = (const float*)d_in[0];
    const float* W1    = (const float*)d_in[1];
    const float* gamma = (const float*)d_in[3];
    const float* beta  = (const float*)d_in[4];
    const float* W2    = (const float*)d_in[5];
    const float* b2    = (const float*)d_in[6];
    const float* V0    = (const float*)d_in[7];
    float* out = (float*)d_out;

    float* ws    = (float*)d_ws;
    float* S     = ws + OFF_S;
    float* sumw2 = ws + OFF_SUMW2;
    unsigned* cnt = (unsigned*)(ws + OFF_CNT);
    unsigned* gen = (unsigned*)(ws + OFF_GEN);
    float* cvec  = ws + OFF_CVEC;
    float* W1s   = ws + OFF_W1S;
    float* wvec  = ws + OFF_WVEC;
    float* Wmat  = ws + OFF_WMAT;
    float* Va    = ws + OFF_VA;
    float* Vb    = ws + OFF_VB;
    float* Spart = ws + OFF_SPART;

    hipMemsetAsync(sumw2, 0, 3 * sizeof(float), stream);           // sumw2, cnt, gen
    hipMemsetAsync(Spart, 0, 64 * 1600 * sizeof(float), stream);   // partial slots
    stats_kernel<<<SBLK, 256, 0, stream>>>(x, Spart);
    reduce_S<<<7, 256, 0, stream>>>(Spart, S);
    bn_prep<<<HID, 64, 0, stream>>>(S, W1, gamma, beta, W1s, cvec);
    mlp_kernel<<<(PP + 255) / 256, 256, 0, stream>>>(x, W1s, cvec, W2, b2, wvec, sumw2);
    buildW<<<dim3(80, 75), 256, 0, stream>>>(wvec, Wmat);
    sdp_fused<<<SDP_BLOCKS, 512, 0, stream>>>(V0, Va, Vb, Wmat, sumw2, cnt, gen);
    // 100 iters: last (it=99, odd) writes Va
    vvt_kernel<<<dim3(10, 10), 256, 0, stream>>>(Va, out);
}